// Round 9
// baseline (3464.278 us; speedup 1.0000x reference)
//
#include <hip/hip_runtime.h>
#include <cstdint>

#define TT 512

typedef float f32x16 __attribute__((ext_vector_type(16)));
typedef short s16x8 __attribute__((ext_vector_type(8)));
typedef unsigned short u16x4 __attribute__((ext_vector_type(4)));

// ---------------- threefry2x32 (exact JAX semantics) ----------------
__host__ __device__ inline void tf2x32(uint32_t k0, uint32_t k1, uint32_t& x0, uint32_t& x1) {
  uint32_t k2 = k0 ^ k1 ^ 0x1BD11BDAu;
#define TF_R(r) { x0 += x1; x1 = (x1 << r) | (x1 >> (32 - r)); x1 ^= x0; }
  x0 += k0; x1 += k1;
  TF_R(13) TF_R(15) TF_R(26) TF_R(6)
  x0 += k1; x1 += k2 + 1u;
  TF_R(17) TF_R(29) TF_R(16) TF_R(24)
  x0 += k2; x1 += k0 + 2u;
  TF_R(13) TF_R(15) TF_R(26) TF_R(6)
  x0 += k0; x1 += k1 + 3u;
  TF_R(17) TF_R(29) TF_R(16) TF_R(24)
  x0 += k1; x1 += k2 + 4u;
  TF_R(13) TF_R(15) TF_R(26) TF_R(6)
  x0 += k2; x1 += k0 + 5u;
#undef TF_R
}

struct KParams {
  const float* input;
  const float* w_ih[4];
  const float* w_hh[4];
  const float* b_ih[4];
  const float* b_hh[4];
  const float* w_lin;
  const float* b_lin;
  unsigned short* hLLC;   // [8][2][32768] bf16 — LLC copy (sc0 sc1)
  unsigned short* hL2;    // [8][2][32768] bf16 — per-XCD L2 copy (sc0)
  uint32_t* cnt;          // kinds: 0=own-ready 1=below-ready 2=reads-done; [3][8][8]x32dw
  uint32_t* xcdtab;       // [256]
  uint32_t* initcnt;      // [1]
  float* out;             // [128][512]
  uint32_t mk[4][2];      // per-layer threefry subkeys (partitionable split)
};

__device__ __forceinline__ unsigned short f2bf(float v) {
  uint32_t u = __float_as_uint(v);
  u += 0x7FFFu + ((u >> 16) & 1u);      // RNE
  return (unsigned short)(u >> 16);
}
__device__ __forceinline__ float bf2f(unsigned short b) {
  return __uint_as_float(((uint32_t)b) << 16);
}
__device__ __forceinline__ float sigm(float x) { return 1.f / (1.f + __expf(-x)); }
__device__ __forceinline__ float tanh_fast(float x) {
  float a = fabsf(x);
  float e = __expf(-2.f * a);
  float r = (1.f - e) / (1.f + e);
  return copysignf(r, x);
}

#define MFMA(A, Bv, C) __builtin_amdgcn_mfma_f32_32x32x16_bf16((A), (Bv), (C), 0, 0, 0)

// counted vmcnt wait (a = load-pairs still allowed in flight)
__device__ __forceinline__ void vmwait_dyn(int a) {
  switch (a) {
    case 0: asm volatile("s_waitcnt vmcnt(0)" ::: "memory"); break;
    case 1: asm volatile("s_waitcnt vmcnt(2)" ::: "memory"); break;
    case 2: asm volatile("s_waitcnt vmcnt(4)" ::: "memory"); break;
    case 3: asm volatile("s_waitcnt vmcnt(6)" ::: "memory"); break;
    case 4: asm volatile("s_waitcnt vmcnt(8)" ::: "memory"); break;
    case 5: asm volatile("s_waitcnt vmcnt(10)" ::: "memory"); break;
    case 6: asm volatile("s_waitcnt vmcnt(12)" ::: "memory"); break;
    case 7: asm volatile("s_waitcnt vmcnt(14)" ::: "memory"); break;
    default: asm volatile("s_waitcnt vmcnt(16)" ::: "memory"); break;
  }
  __builtin_amdgcn_sched_barrier(0);
}

#define ISSUE_LLC(s0, s1, ptr) \
  asm volatile("global_load_dwordx4 %0, %2, off sc0 sc1\n\t" \
               "global_load_dwordx4 %1, %2, off offset:1024 sc0 sc1" \
               : "=&v"(s0), "=&v"(s1) : "v"(ptr) : "memory")
#define ISSUE_L2(s0, s1, ptr) \
  asm volatile("global_load_dwordx4 %0, %2, off sc0\n\t" \
               "global_load_dwordx4 %1, %2, off offset:1024 sc0" \
               : "=&v"(s0), "=&v"(s1) : "v"(ptr) : "memory")

// rolling-pipelined GEMM: k-block of frag i = i*KSTRIDE + koff; PRECONDITION vmcnt==0.
template <int NIT, int KSTRIDE, bool L2MODE>
__device__ __forceinline__ void gemm_roll(const unsigned short* buf, int koff,
                                          const s16x8 (&Wh)[2][16], const s16x8 (&Wl)[2][16],
                                          int lane,
                                          f32x16& a00, f32x16& a01, f32x16& a10, f32x16& a11) {
  constexpr int D = 8;
  constexpr int S = 9;                    // issue slot never aliases a pending read
  s16x8 st[S][2];
  const unsigned short* base = buf + koff * 1024 + lane * 8;
#pragma unroll
  for (int i = 0; i < (NIT < D ? NIT : D); ++i) {
    const unsigned short* ptr = base + i * KSTRIDE * 1024;
    if constexpr (L2MODE) { ISSUE_L2(st[i % S][0], st[i % S][1], ptr); }
    else                  { ISSUE_LLC(st[i % S][0], st[i % S][1], ptr); }
  }
#pragma unroll
  for (int i = 0; i < NIT; ++i) {
    if (i + D < NIT) {
      const unsigned short* ptr = base + (i + D) * KSTRIDE * 1024;
      if constexpr (L2MODE) { ISSUE_L2(st[(i + D) % S][0], st[(i + D) % S][1], ptr); }
      else                  { ISSUE_LLC(st[(i + D) % S][0], st[(i + D) % S][1], ptr); }
    }
    vmwait_dyn((NIT - 1 - i) < D ? (NIT - 1 - i) : D);
    s16x8 bh0 = st[i % S][0];
    s16x8 bh1 = st[i % S][1];
    a00 = MFMA(Wh[0][i], bh0, a00);
    a10 = MFMA(Wh[1][i], bh0, a10);
    a01 = MFMA(Wh[0][i], bh1, a01);
    a11 = MFMA(Wh[1][i], bh1, a11);
    a00 = MFMA(Wl[0][i], bh0, a00);
    a10 = MFMA(Wl[1][i], bh0, a10);
    a01 = MFMA(Wl[0][i], bh1, a01);
    a11 = MFMA(Wl[1][i], bh1, a11);
  }
}

// single-dword monotone-counter poll (all lanes same address -> broadcast)
__device__ __forceinline__ void pollcnt(const uint32_t* p, uint32_t tgt, bool slp) {
  while (__hip_atomic_load(p, __ATOMIC_RELAXED, __HIP_MEMORY_SCOPE_AGENT) < tgt) {
    if (slp) __builtin_amdgcn_s_sleep(1);
  }
}
__device__ __forceinline__ uint32_t tgt_of(int T) { return 32u * ((uint32_t)(T >> 3) + 1u); }

__global__ __launch_bounds__(256, 1) void lstm4(KParams P) {
  const int wg   = blockIdx.x;
  const int grp  = wg & 7;       // (layer, half) — one XCD per group under round-robin
  const int iwg  = wg >> 3;      // 0..31: which 16-unit slice
  const int l    = grp >> 1;
  const int p    = grp & 1;
  const int tid  = threadIdx.x;
  const int wave = tid >> 6;
  const int lane = tid & 63;

  __shared__ float part[4][64][64];   // 64 KB
  __shared__ float bias_s[64];
  __shared__ float wih1_s[64];
  __shared__ float wlin_s[16];
  __shared__ float red_s[4][64];
  __shared__ uint32_t xs[8];
  __shared__ uint32_t barflag;

  uint32_t* const cb = P.cnt;
#define CNT(kind, g, slot) (cb + (((kind) * 8 + (g)) * 8 + (slot)) * 32)

  // ---- XCD identity probe
  uint32_t xcd;
  asm volatile("s_getreg_b32 %0, hwreg(20, 0, 4)" : "=s"(xcd));
  if (tid == 0) {
    __hip_atomic_store(&P.xcdtab[wg], xcd, __ATOMIC_RELAXED, __HIP_MEMORY_SCOPE_AGENT);
    asm volatile("s_waitcnt vmcnt(0)" ::: "memory");
    __hip_atomic_fetch_add(P.initcnt, 1u, __ATOMIC_RELAXED, __HIP_MEMORY_SCOPE_AGENT);
  }

  // ---- weight fragments (hi + lo bf16) into registers, per wave role:
  //  l==0          : all waves own-half (w_hh, K=512), 4-way k-split, frags 0..7
  //  l>0, wave 0-1 : below-half (w_ih, K=512->1024 cols 0..511), 2-way split, frags 0..15
  //  l>0, wave 2-3 : own-half (w_hh), 2-way split, frags 0..15
  s16x8 Whi[2][16], Wlo[2][16];
  {
#pragma unroll
    for (int ji = 0; ji < 16; ++ji) {
      bool valid = true;
      int blk;
      const float* wsrc;
      if (l == 0) { valid = (ji < 8); blk = (ji & 7) * 4 + wave; wsrc = P.w_hh[0]; }
      else if (wave < 2) { blk = ji * 2 + (wave & 1); wsrc = P.w_ih[l]; }
      else               { blk = ji * 2 + (wave & 1); wsrc = P.w_hh[l]; }
      const int col = blk * 16 + (lane >> 5) * 8;
#pragma unroll
      for (int m = 0; m < 2; ++m) {
        const int rl = m * 32 + (lane & 31);
        const int grow = (rl >> 4) * 512 + iwg * 16 + (rl & 15);
        s16x8 h8 = {0, 0, 0, 0, 0, 0, 0, 0};
        s16x8 l8 = {0, 0, 0, 0, 0, 0, 0, 0};
        if (valid) {
          const float* s = wsrc + grow * 512 + col;
#pragma unroll
          for (int e = 0; e < 8; ++e) {
            float v = s[e];
            unsigned short hb = f2bf(v);
            h8[e] = (short)hb;
            l8[e] = (short)f2bf(v - bf2f(hb));
          }
        }
        Whi[m][ji] = h8;
        Wlo[m][ji] = l8;
      }
    }
  }
  if (tid < 64) {
    const int rl = tid;
    const int grow = (rl >> 4) * 512 + iwg * 16 + (rl & 15);
    bias_s[rl] = P.b_ih[l][grow] + P.b_hh[l][grow];
    wih1_s[rl] = (l == 0) ? P.w_ih[0][grow] : 0.f;
  }
  if (l == 3 && tid < 16) wlin_s[tid] = P.w_lin[iwg * 16 + tid];

  // ---- bounded grid init barrier (timeout -> LLC-only fallback, never hang)
  if (tid == 0) {
    uint32_t okv = 1u, tries = 0u;
    while (__hip_atomic_load(P.initcnt, __ATOMIC_RELAXED, __HIP_MEMORY_SCOPE_AGENT) < 256u) {
      __builtin_amdgcn_s_sleep(8);
      if (++tries > (1u << 17)) { okv = 0u; break; }
    }
    barflag = okv;
  }
  __syncthreads();
  const bool bar_ok = (barflag != 0u);

  // ---- XCD-mapping verification
  uint32_t va = __hip_atomic_load(&P.xcdtab[tid], __ATOMIC_RELAXED, __HIP_MEMORY_SCOPE_AGENT);
  uint32_t vb = __hip_atomic_load(&P.xcdtab[tid & 7], __ATOMIC_RELAXED, __HIP_MEMORY_SCOPE_AGENT);
  int ok1 = __syncthreads_and((va == vb) ? 1 : 0);
  if (tid < 8) xs[tid] = vb;
  __syncthreads();
  bool dis = true;
#pragma unroll
  for (int a = 0; a < 8; ++a)
#pragma unroll
    for (int b = a + 1; b < 8; ++b)
      if (xs[a] == xs[b]) dis = false;
  const bool l2ok = bar_ok && (ok1 != 0) && dis;
  __syncthreads();

  const int gb = p * 64 + lane;
  const uint32_t kk0 = P.mk[l][0], kk1 = P.mk[l][1];
  float cst[4] = {0.f, 0.f, 0.f, 0.f};

  for (int t = 0; t < TT; ++t) {
    float xin = 0.f;
    if (l == 0) xin = P.input[gb * 512 + t];

    f32x16 a00 = {0,0,0,0,0,0,0,0,0,0,0,0,0,0,0,0};
    f32x16 a01 = {0,0,0,0,0,0,0,0,0,0,0,0,0,0,0,0};
    f32x16 a10 = {0,0,0,0,0,0,0,0,0,0,0,0,0,0,0,0};
    f32x16 a11 = {0,0,0,0,0,0,0,0,0,0,0,0,0,0,0,0};

    const unsigned short* pB    = P.hLLC + (size_t)(((l - 1) * 2 + p) * 2 + (t & 1)) * 32768;
    const unsigned short* pOL2  = P.hL2  + (size_t)(grp * 2 + ((t - 1) & 1)) * 32768;
    const unsigned short* pOLLC = P.hLLC + (size_t)(grp * 2 + ((t - 1) & 1)) * 32768;

    // ---- concurrent GEMM halves via wave roles ----
    if (l > 0) {
      if (wave < 2) {           // below half (cross-layer edge: a beat of slack)
        pollcnt(CNT(1, grp - 2, t & 7), tgt_of(t), true);
        asm volatile("s_waitcnt vmcnt(0)" ::: "memory");
        gemm_roll<16, 2, false>(pB, wave & 1, Whi, Wlo, lane, a00, a01, a10, a11);
      } else if (t > 0) {       // own half (critical recurrent edge)
        pollcnt(CNT(0, grp, (t - 1) & 7), tgt_of(t - 1), false);
        asm volatile("s_waitcnt vmcnt(0)" ::: "memory");
        if (l2ok) gemm_roll<16, 2, true >(pOL2,  wave & 1, Whi, Wlo, lane, a00, a01, a10, a11);
        else      gemm_roll<16, 2, false>(pOLLC, wave & 1, Whi, Wlo, lane, a00, a01, a10, a11);
      }
    } else if (t > 0) {
      pollcnt(CNT(0, grp, (t - 1) & 7), tgt_of(t - 1), false);
      asm volatile("s_waitcnt vmcnt(0)" ::: "memory");
      if (l2ok) gemm_roll<8, 4, true >(pOL2,  wave, Whi, Wlo, lane, a00, a01, a10, a11);
      else      gemm_roll<8, 4, false>(pOLLC, wave, Whi, Wlo, lane, a00, a01, a10, a11);
    }

    // ---- single-phase cross-wave reduction (sums below+own partials) ----
#pragma unroll
    for (int r = 0; r < 16; ++r) {
      const int row = (r & 3) + 8 * (r >> 2) + 4 * (lane >> 5);
      const int cl = lane & 31;
      part[wave][row][cl]           = a00[r];
      part[wave][row][32 + cl]      = a01[r];
      part[wave][32 + row][cl]      = a10[r];
      part[wave][32 + row][32 + cl] = a11[r];
    }

    // dropout factors (threefry) in the barrier shadow
    float fac[4];
#pragma unroll
    for (int cc = 0; cc < 4; ++cc) {
      const int gu = iwg * 16 + wave * 4 + cc;
      uint32_t j = ((uint32_t)t * 128u + (uint32_t)gb) * 512u + (uint32_t)gu;
      uint32_t x0 = 0u, x1 = j;
      tf2x32(kk0, kk1, x0, x1);
      fac[cc] = ((x0 ^ x1) & 0x80000000u) ? 0.f : 2.f;
    }
    __syncthreads();
    // reads-done publish: all waves' GEMM loads retired before the barrier
    if (tid == 0 && l > 0)
      __hip_atomic_fetch_add(CNT(2, grp, t & 7), 1u, __ATOMIC_RELAXED, __HIP_MEMORY_SCOPE_AGENT);

    float si[4], sf[4], sg[4], so[4];
#pragma unroll
    for (int cc = 0; cc < 4; ++cc) {
      const int ul = wave * 4 + cc;
      si[cc] = part[0][ul][lane]      + part[1][ul][lane]      + part[2][ul][lane]      + part[3][ul][lane];
      sf[cc] = part[0][16 + ul][lane] + part[1][16 + ul][lane] + part[2][16 + ul][lane] + part[3][16 + ul][lane];
      sg[cc] = part[0][32 + ul][lane] + part[1][32 + ul][lane] + part[2][32 + ul][lane] + part[3][32 + ul][lane];
      so[cc] = part[0][48 + ul][lane] + part[1][48 + ul][lane] + part[2][48 + ul][lane] + part[3][48 + ul][lane];
    }

    // ---- elementwise LSTM cell ----
    float osum = 0.f;
    u16x4 hv;
#pragma unroll
    for (int cc = 0; cc < 4; ++cc) {
      const int ul = wave * 4 + cc;
      float pi = si[cc] + bias_s[ul];
      float pf = sf[cc] + bias_s[16 + ul];
      float pg = sg[cc] + bias_s[32 + ul];
      float po = so[cc] + bias_s[48 + ul];
      if (l == 0) {
        pi += wih1_s[ul] * xin;
        pf += wih1_s[16 + ul] * xin;
        pg += wih1_s[32 + ul] * xin;
        po += wih1_s[48 + ul] * xin;
      }
      float ig = sigm(pi), fg = sigm(pf), gg = tanh_fast(pg), og = sigm(po);
      float cn = fg * cst[cc] + ig * gg;
      cst[cc] = cn;
      float hh = og * tanh_fast(cn) * fac[cc];
      hv[cc] = f2bf(hh);
      if (l == 3) osum += hh * wlin_s[ul];
    }

    // ---- eviction guard: layer-above finished reading our hLLC slot (t-2)
    if (l < 3 && t >= 2)
      pollcnt(CNT(2, grp + 2, (t - 2) & 7), tgt_of(t - 2), true);

    // ---- stores: hL2 FIRST, then hLLC; early own-publish on L2 ack ----
    {
      const int elem = ((iwg * 2 + (lane >> 5)) * 64 + (wave >> 1) * 32 + (lane & 31)) * 8 + (wave & 1) * 4;
      unsigned short* wLLC = P.hLLC + (size_t)(grp * 2 + (t & 1)) * 32768 + elem;
      unsigned short* wL2  = P.hL2  + (size_t)(grp * 2 + (t & 1)) * 32768 + elem;
      const bool llcstore = (l < 3) || (!l2ok);
      if (l2ok)
        asm volatile("global_store_dwordx2 %0, %1, off sc0" :: "v"(wL2), "v"(hv) : "memory");
      if (llcstore)
        asm volatile("global_store_dwordx2 %0, %1, off sc0 sc1" :: "v"(wLLC), "v"(hv) : "memory");

      if (l2ok) {
        if (llcstore) { asm volatile("s_waitcnt vmcnt(1)" ::: "memory"); }
        else          { asm volatile("s_waitcnt vmcnt(0)" ::: "memory"); }
        __syncthreads();
        if (tid == 0)   // own-ready: L2 copy visible to same-XCD consumers
          __hip_atomic_fetch_add(CNT(0, grp, t & 7), 1u, __ATOMIC_RELAXED, __HIP_MEMORY_SCOPE_AGENT);
        if (llcstore) {
          asm volatile("s_waitcnt vmcnt(0)" ::: "memory");
          __syncthreads();
          if (tid == 0 && l < 3)
            __hip_atomic_fetch_add(CNT(1, grp, t & 7), 1u, __ATOMIC_RELAXED, __HIP_MEMORY_SCOPE_AGENT);
        }
      } else {
        asm volatile("s_waitcnt vmcnt(0)" ::: "memory");
        __syncthreads();
        if (tid == 0) {
          __hip_atomic_fetch_add(CNT(0, grp, t & 7), 1u, __ATOMIC_RELAXED, __HIP_MEMORY_SCOPE_AGENT);
          if (l < 3)
            __hip_atomic_fetch_add(CNT(1, grp, t & 7), 1u, __ATOMIC_RELAXED, __HIP_MEMORY_SCOPE_AGENT);
        }
      }
    }

    // ---- layer-3 projection (after publish) ----
    if (l == 3) {
      red_s[wave][lane] = osum;
      __syncthreads();
      if (tid < 64) {
        float v = red_s[0][tid] + red_s[1][tid] + red_s[2][tid] + red_s[3][tid];
        if (iwg == 0) v += P.b_lin[0];
        atomicAdd(&P.out[(p * 64 + tid) * 512 + t], v);
      }
    }
  }
#undef CNT
}

extern "C" void kernel_launch(void* const* d_in, const int* in_sizes, int n_in,
                              void* d_out, int out_size, void* d_ws, size_t ws_size,
                              hipStream_t stream) {
  (void)in_sizes; (void)n_in; (void)ws_size;
  KParams P;
  P.input = (const float*)d_in[0];
  for (int l = 0; l < 4; ++l) {
    P.w_ih[l] = (const float*)d_in[1 + 4 * l];
    P.w_hh[l] = (const float*)d_in[2 + 4 * l];
    P.b_ih[l] = (const float*)d_in[3 + 4 * l];
    P.b_hh[l] = (const float*)d_in[4 + 4 * l];
  }
  P.w_lin = (const float*)d_in[17];
  P.b_lin = (const float*)d_in[18];
  unsigned char* ws = (unsigned char*)d_ws;
  P.hLLC    = (unsigned short*)(ws);                          // 1 MB   [8][2][32768]
  P.hL2     = (unsigned short*)(ws + (1u << 20));             // 1 MB   [8][2][32768]
  P.cnt     = (uint32_t*)(ws + (2u << 20));                   // 24 KB  [3][8][8] x 128B
  P.xcdtab  = (uint32_t*)(ws + (2u << 20) + (24u << 10));     // 1 KB
  P.initcnt = (uint32_t*)(ws + (2u << 20) + (24u << 10) + 1024);
  P.out     = (float*)d_out;
  // total ws span ~2.03 MB (<= 2.62 MB proven by R2/R3)

  // subkeys = jax.random.split(key(42), 4) under threefry_partitionable=True
  for (uint32_t i = 0; i < 4; ++i) {
    uint32_t x0 = 0u, x1 = i;
    tf2x32(0u, 42u, x0, x1);
    P.mk[i][0] = x0; P.mk[i][1] = x1;
  }

  hipMemsetAsync(P.cnt, 0, 3 * 8 * 8 * 32 * sizeof(uint32_t), stream);
  hipMemsetAsync(P.xcdtab, 0, 2048, stream);                  // xcdtab + initcnt
  hipMemsetAsync(d_out, 0, (size_t)out_size * sizeof(float), stream);
  hipLaunchKernelGGL(lstm4, dim3(256), dim3(256), 0, stream, P);
}